// Round 2
// baseline (1067.990 us; speedup 1.0000x reference)
//
#include <hip/hip_runtime.h>

typedef __attribute__((ext_vector_type(8))) short s16x8;
typedef __attribute__((ext_vector_type(4))) float f32x4;

#define TN 288

__device__ __forceinline__ unsigned short f2bf(float f) {
  union { float f; unsigned u; } v; v.f = f;
  unsigned r = v.u + 0x7fffu + ((v.u >> 16) & 1u);
  return (unsigned short)(r >> 16);
}
__device__ __forceinline__ float bf2f(unsigned short u) {
  union { float f; unsigned u; } v; v.u = ((unsigned)u) << 16;
  return v.f;
}

// ---------------- f32 -> bf16 cast (n % 4 == 0) ----------------
__global__ __launch_bounds__(256) void cast_kernel(const float* __restrict__ in,
    unsigned short* __restrict__ out, long n) {
  for (long i = ((long)blockIdx.x * 256 + threadIdx.x) * 4; i < n;
       i += (long)gridDim.x * 1024) {
    float4 f = *(const float4*)(in + i);
    unsigned lo = (unsigned)f2bf(f.x) | ((unsigned)f2bf(f.y) << 16);
    unsigned hi = (unsigned)f2bf(f.z) | ((unsigned)f2bf(f.w) << 16);
    *(uint2*)(out + i) = make_uint2(lo, hi);
  }
}

// ---------------- onehot = I_mat[(i+t)%TN] @ oh_W + oh_b ----------------
__global__ __launch_bounds__(256) void onehot_kernel(const int* __restrict__ pi,
    const float* __restrict__ I_mat, const float* __restrict__ ohW,
    const float* __restrict__ ohb, float* __restrict__ onehot) {
  int t = blockIdx.x;
  int r = (pi[0] + t) % TN;
  int e = threadIdx.x;
  float acc0 = ohb[e], acc1 = ohb[e + 256];
  const float* Ir = I_mat + (size_t)r * TN;
  for (int j = 0; j < TN; ++j) {
    float iv = Ir[j];
    acc0 += iv * ohW[(size_t)j * 512 + e];
    acc1 += iv * ohW[(size_t)j * 512 + e + 256];
  }
  onehot[(size_t)t * 512 + e] = acc0;
  onehot[(size_t)t * 512 + e + 256] = acc1;
}

// ---------------- projection GEMM: C(bf16) = A(f32 [+onehot]) @ B(bf16) ----
// BM=BN=64, BK=32, 4 waves 2x2, each wave 32x32 (2x2 frags of 16x16x32)
template<bool QIN>
__global__ __launch_bounds__(256) void proj_gemm(const float* __restrict__ A,
    const unsigned short* __restrict__ B, const float* __restrict__ onehot,
    unsigned short* __restrict__ C, int M, int N, int K) {
  __shared__ unsigned short As[64][40];
  __shared__ unsigned short Bs[64][40];   // Bs[col][k]
  const int m0 = blockIdx.x * 64, n0 = blockIdx.y * 64;
  const int tid = threadIdx.x, w = tid >> 6, l = tid & 63, lr = l & 15, lg = l >> 4;
  const int wr = (w >> 1) * 32, wc = (w & 1) * 32;
  const int aRow = (tid * 8) >> 5, aK = (tid * 8) & 31;
  const int bK = (tid * 8) >> 6, bCol = (tid * 8) & 63;
  f32x4 acc[2][2] = {};
  for (int kb = 0; kb < K; kb += 32) {
    size_t fl = (size_t)(m0 + aRow) * K + kb + aK;
    float4 f0 = *(const float4*)(A + fl);
    float4 f1 = *(const float4*)(A + fl + 4);
    if (QIN) {
      const float* oh = onehot + (fl & 262143);
      float4 o0 = *(const float4*)(oh);
      float4 o1 = *(const float4*)(oh + 4);
      f0.x += o0.x; f0.y += o0.y; f0.z += o0.z; f0.w += o0.w;
      f1.x += o1.x; f1.y += o1.y; f1.z += o1.z; f1.w += o1.w;
    }
    s16x8 av;
    av[0] = (short)f2bf(f0.x); av[1] = (short)f2bf(f0.y);
    av[2] = (short)f2bf(f0.z); av[3] = (short)f2bf(f0.w);
    av[4] = (short)f2bf(f1.x); av[5] = (short)f2bf(f1.y);
    av[6] = (short)f2bf(f1.z); av[7] = (short)f2bf(f1.w);
    *(s16x8*)&As[aRow][aK] = av;
    s16x8 bv = *(const s16x8*)(B + (size_t)(kb + bK) * N + n0 + bCol);
#pragma unroll
    for (int j = 0; j < 8; ++j) Bs[bCol + j][bK] = (unsigned short)bv[j];
    __syncthreads();
    s16x8 af0 = *(const s16x8*)&As[wr + lr][lg * 8];
    s16x8 af1 = *(const s16x8*)&As[wr + 16 + lr][lg * 8];
    s16x8 bf0 = *(const s16x8*)&Bs[wc + lr][lg * 8];
    s16x8 bf1 = *(const s16x8*)&Bs[wc + 16 + lr][lg * 8];
    acc[0][0] = __builtin_amdgcn_mfma_f32_16x16x32_bf16(af0, bf0, acc[0][0], 0, 0, 0);
    acc[0][1] = __builtin_amdgcn_mfma_f32_16x16x32_bf16(af0, bf1, acc[0][1], 0, 0, 0);
    acc[1][0] = __builtin_amdgcn_mfma_f32_16x16x32_bf16(af1, bf0, acc[1][0], 0, 0, 0);
    acc[1][1] = __builtin_amdgcn_mfma_f32_16x16x32_bf16(af1, bf1, acc[1][1], 0, 0, 0);
    __syncthreads();
  }
#pragma unroll
  for (int fi = 0; fi < 2; ++fi)
#pragma unroll
    for (int fj = 0; fj < 2; ++fj)
#pragma unroll
      for (int r = 0; r < 4; ++r) {
        int row = m0 + wr + fi * 16 + lg * 4 + r;
        int col = n0 + wc + fj * 16 + lr;
        C[(size_t)row * N + col] = f2bf(acc[fi][fj][r]);
      }
}

// ---------------- big GEMM: C = A(bf16)@B(bf16) + (bias | C_old) [, relu] --
// BM=BN=128, BK=32, 4 waves 2x2, each wave 64x64 (4x4 frags)
template<bool RELU, bool OUTBF, bool ACC>
__global__ __launch_bounds__(256) void gemm128(const unsigned short* __restrict__ A,
    int lda, const unsigned short* __restrict__ B, int ldb,
    const float* __restrict__ bias, void* __restrict__ Cout, int ldc,
    int M, int N, int K) {
  __shared__ unsigned short As[128][40];
  __shared__ unsigned short Bs[128][40];  // Bs[col][k]
  const int m0 = blockIdx.x * 128, n0 = blockIdx.y * 128;
  const int tid = threadIdx.x, w = tid >> 6, l = tid & 63, lr = l & 15, lg = l >> 4;
  const int wr = (w >> 1) * 64, wc = (w & 1) * 64;
  const int t8 = tid * 8;
  f32x4 acc[4][4] = {};
  for (int kb = 0; kb < K; kb += 32) {
#pragma unroll
    for (int it = 0; it < 2; ++it) {
      int idx = t8 + it * 2048;
      int row = idx >> 5, kk = idx & 31;
      *(s16x8*)&As[row][kk] = *(const s16x8*)(A + (size_t)(m0 + row) * lda + kb + kk);
    }
#pragma unroll
    for (int it = 0; it < 2; ++it) {
      int idx = t8 + it * 2048;
      int kk = idx >> 7, col = idx & 127;
      s16x8 bv = *(const s16x8*)(B + (size_t)(kb + kk) * ldb + n0 + col);
#pragma unroll
      for (int j = 0; j < 8; ++j) Bs[col + j][kk] = (unsigned short)bv[j];
    }
    __syncthreads();
    s16x8 af[4], bfv[4];
#pragma unroll
    for (int fi = 0; fi < 4; ++fi) af[fi] = *(const s16x8*)&As[wr + fi * 16 + lr][lg * 8];
#pragma unroll
    for (int fj = 0; fj < 4; ++fj) bfv[fj] = *(const s16x8*)&Bs[wc + fj * 16 + lr][lg * 8];
#pragma unroll
    for (int fi = 0; fi < 4; ++fi)
#pragma unroll
      for (int fj = 0; fj < 4; ++fj)
        acc[fi][fj] = __builtin_amdgcn_mfma_f32_16x16x32_bf16(af[fi], bfv[fj], acc[fi][fj], 0, 0, 0);
    __syncthreads();
  }
#pragma unroll
  for (int fj = 0; fj < 4; ++fj) {
    int col = n0 + wc + fj * 16 + lr;
    float bv = ACC ? 0.f : bias[col];
#pragma unroll
    for (int fi = 0; fi < 4; ++fi)
#pragma unroll
      for (int r = 0; r < 4; ++r) {
        int row = m0 + wr + fi * 16 + lg * 4 + r;
        size_t ci = (size_t)row * ldc + col;
        float base = ACC ? ((const float*)Cout)[ci] : bv;
        float v = acc[fi][fj][r] + base;
        if (RELU) v = fmaxf(v, 0.f);
        if (OUTBF) ((unsigned short*)Cout)[ci] = f2bf(v);
        else ((float*)Cout)[ci] = v;
      }
  }
}

// ---------------- attention: block = (qt, h, n); 4 waves x 16 q-rows ------
__global__ __launch_bounds__(256) void attn_kernel(
    const unsigned short* __restrict__ Qp, const unsigned short* __restrict__ Kp,
    const unsigned short* __restrict__ Vp, unsigned short* __restrict__ Out) {
  __shared__ unsigned short KV[128][72];       // K chunk then V chunk
  __shared__ unsigned short P[4][16][136];     // per-wave P tile
  const int qt = blockIdx.x, h = blockIdx.y, n = blockIdx.z;
  const int tid = threadIdx.x, w = tid >> 6, l = tid & 63, lr = l & 15, lg = l >> 4;
  const float scale = 0.044194173824159216f;   // 1/sqrt(512)

  const int qrow_a = qt * 64 + w * 16 + lr;
  const size_t qbase = (((size_t)(n * 512 + qrow_a)) * 8 + h) * 64;
  s16x8 qf0 = *(const s16x8*)(Qp + qbase + lg * 8);
  s16x8 qf1 = *(const s16x8*)(Qp + qbase + 32 + lg * 8);

  f32x4 sacc[32] = {};

  // pass 1: S = Q K^T
  for (int c = 0; c < 4; ++c) {
    __syncthreads();
#pragma unroll
    for (int it = 0; it < 4; ++it) {
      int idx = (tid + it * 256) * 8;
      int rr = idx >> 6, d = idx & 63;
      s16x8 kv = *(const s16x8*)(Kp + (((size_t)(n * 512 + c * 128 + rr)) * 8 + h) * 64 + d);
      *(s16x8*)&KV[rr][d] = kv;
    }
    __syncthreads();
#pragma unroll
    for (int f = 0; f < 8; ++f) {
      s16x8 b0 = *(const s16x8*)&KV[f * 16 + lr][lg * 8];
      s16x8 b1 = *(const s16x8*)&KV[f * 16 + lr][32 + lg * 8];
      f32x4 a = sacc[c * 8 + f];
      a = __builtin_amdgcn_mfma_f32_16x16x32_bf16(qf0, b0, a, 0, 0, 0);
      a = __builtin_amdgcn_mfma_f32_16x16x32_bf16(qf1, b1, a, 0, 0, 0);
      sacc[c * 8 + f] = a;
    }
  }

  // softmax (exact, full row in registers); row r of D: lanes lg group, reg r
  float ps[4];
#pragma unroll
  for (int r = 0; r < 4; ++r) {
    float m = -1e30f;
#pragma unroll
    for (int f = 0; f < 32; ++f) m = fmaxf(m, sacc[f][r]);
#pragma unroll
    for (int mk = 1; mk < 16; mk <<= 1) m = fmaxf(m, __shfl_xor(m, mk));
    float s = 0.f;
#pragma unroll
    for (int f = 0; f < 32; ++f) {
      float p = __expf((sacc[f][r] - m) * scale);
      sacc[f][r] = p; s += p;
    }
#pragma unroll
    for (int mk = 1; mk < 16; mk <<= 1) s += __shfl_xor(s, mk);
    ps[r] = 1.f / s;
  }

  // pass 2: O = P V
  f32x4 oacc[4] = {};
  for (int c = 0; c < 4; ++c) {
    __syncthreads();
#pragma unroll
    for (int it = 0; it < 4; ++it) {
      int idx = (tid + it * 256) * 8;
      int rr = idx >> 6, d = idx & 63;
      s16x8 vv = *(const s16x8*)(Vp + (((size_t)(n * 512 + c * 128 + rr)) * 8 + h) * 64 + d);
      *(s16x8*)&KV[rr][d] = vv;
    }
#pragma unroll
    for (int f = 0; f < 8; ++f)
#pragma unroll
      for (int r = 0; r < 4; ++r)
        P[w][lg * 4 + r][f * 16 + lr] = f2bf(sacc[c * 8 + f][r] * ps[r]);
    __syncthreads();
#pragma unroll
    for (int ks = 0; ks < 4; ++ks) {
      s16x8 pa = *(const s16x8*)&P[w][lr][ks * 32 + lg * 8];
#pragma unroll
      for (int fj = 0; fj < 4; ++fj) {
        s16x8 bv;
#pragma unroll
        for (int j = 0; j < 8; ++j)
          bv[j] = (short)KV[ks * 32 + lg * 8 + j][fj * 16 + lr];
        oacc[fj] = __builtin_amdgcn_mfma_f32_16x16x32_bf16(pa, bv, oacc[fj], 0, 0, 0);
      }
    }
  }
#pragma unroll
  for (int fj = 0; fj < 4; ++fj)
#pragma unroll
    for (int r = 0; r < 4; ++r) {
      int qrow = qt * 64 + w * 16 + lg * 4 + r;
      Out[((size_t)(n * 512 + qrow)) * 512 + h * 64 + fj * 16 + lr] = f2bf(oacc[fj][r]);
    }
}

// ---------------- layernorm: 1 wave per 512-elem row, fused residual ------
// XBF: X is bf16; RBF: R is bf16; QIN: add onehot (f32, row t = row&511)
template<bool XBF, bool RBF, bool QIN, bool OUTBF>
__global__ __launch_bounds__(256) void ln_kernel(const void* __restrict__ Xv,
    const void* __restrict__ Rv, const float* __restrict__ onehot,
    const float* __restrict__ g, const float* __restrict__ bb,
    void* __restrict__ outv) {
  int row = blockIdx.x * 4 + (threadIdx.x >> 6);
  int l = threadIdx.x & 63;
  size_t base = (size_t)row * 512 + l * 8;
  float v[8];
  if (XBF) {
    s16x8 xv = *(const s16x8*)((const unsigned short*)Xv + base);
#pragma unroll
    for (int j = 0; j < 8; ++j) v[j] = bf2f((unsigned short)xv[j]);
  } else {
    const float* X = (const float*)Xv;
    float4 x0 = *(const float4*)(X + base);
    float4 x1 = *(const float4*)(X + base + 4);
    v[0] = x0.x; v[1] = x0.y; v[2] = x0.z; v[3] = x0.w;
    v[4] = x1.x; v[5] = x1.y; v[6] = x1.z; v[7] = x1.w;
  }
  if (RBF) {
    s16x8 rv = *(const s16x8*)((const unsigned short*)Rv + base);
#pragma unroll
    for (int j = 0; j < 8; ++j) v[j] += bf2f((unsigned short)rv[j]);
  } else {
    const float* R = (const float*)Rv;
    float4 r0 = *(const float4*)(R + base);
    float4 r1 = *(const float4*)(R + base + 4);
    v[0] += r0.x; v[1] += r0.y; v[2] += r0.z; v[3] += r0.w;
    v[4] += r1.x; v[5] += r1.y; v[6] += r1.z; v[7] += r1.w;
  }
  if (QIN) {
    size_t ob = (size_t)(row & 511) * 512 + l * 8;
    float4 o0 = *(const float4*)(onehot + ob);
    float4 o1 = *(const float4*)(onehot + ob + 4);
    v[0] += o0.x; v[1] += o0.y; v[2] += o0.z; v[3] += o0.w;
    v[4] += o1.x; v[5] += o1.y; v[6] += o1.z; v[7] += o1.w;
  }
  float s = 0.f, ss = 0.f;
#pragma unroll
  for (int j = 0; j < 8; ++j) { s += v[j]; ss += v[j] * v[j]; }
#pragma unroll
  for (int mk = 1; mk < 64; mk <<= 1) { s += __shfl_xor(s, mk); ss += __shfl_xor(ss, mk); }
  float mu = s * (1.f / 512.f);
  float inv = rsqrtf(ss * (1.f / 512.f) - mu * mu + 1e-5f);
#pragma unroll
  for (int j = 0; j < 8; ++j) {
    int e = l * 8 + j;
    float y = (v[j] - mu) * inv * g[e] + bb[e];
    if (OUTBF) ((unsigned short*)outv)[base + j] = f2bf(y);
    else ((float*)outv)[base + j] = y;
  }
}

extern "C" void kernel_launch(void* const* d_in, const int* in_sizes, int n_in,
                              void* d_out, int out_size, void* d_ws, size_t ws_size,
                              hipStream_t stream) {
  const float* value  = (const float*)d_in[0];
  const float* key_in = (const float*)d_in[1];
  const float* query  = (const float*)d_in[2];
  const int*   pi     = (const int*)d_in[3];
  const float* I_mat  = (const float*)d_in[4];
  const float* ohW    = (const float*)d_in[5];
  const float* ohb    = (const float*)d_in[6];
  const float* Wv     = (const float*)d_in[7];
  const float* Wk     = (const float*)d_in[8];
  const float* Wq     = (const float*)d_in[9];
  const float* Wo     = (const float*)d_in[10];
  const float* bo     = (const float*)d_in[11];
  const float* g1     = (const float*)d_in[12];
  const float* b1     = (const float*)d_in[13];
  const float* g2     = (const float*)d_in[14];
  const float* b2     = (const float*)d_in[15];
  const float* W1     = (const float*)d_in[16];
  const float* bf1    = (const float*)d_in[17];
  const float* W2     = (const float*)d_in[18];
  const float* bf2    = (const float*)d_in[19];

  char* ws = (char*)d_ws;
  const size_t MB = 1024 * 1024;
  // d_out doubles as scratch: bf16 q_p (32MB) + k_p (32MB); later ff2/out f32.
  unsigned short* q_p  = (unsigned short*)d_out;
  unsigned short* k_p  = q_p + 16777216;
  unsigned short* v_p    = (unsigned short*)(ws + 0);        // 32MB
  unsigned short* attn_o = (unsigned short*)(ws + 32 * MB);  // 32MB
  unsigned short* x_b    = (unsigned short*)(ws + 64 * MB);  // 32MB (Wo out -> LN1 in place)
  unsigned short* ff1c   = (unsigned short*)(ws + 0);        // 64MB chunk (aliases v_p/attn_o, dead)
  float*          onehot = (float*)(ws + 96 * MB);           // 1MB
  unsigned short* Wv_b   = (unsigned short*)(ws + 97 * MB);
  unsigned short* Wk_b   = Wv_b + 4096;
  unsigned short* Wq_b   = Wk_b + 4096;
  unsigned short* Wo_b   = Wq_b + 4096;
  unsigned short* W1_b   = Wo_b + 262144;
  unsigned short* W2_b   = W1_b + 1048576;
  // peak ws use: 96MB big + ~5.6MB small = ~102MB

  cast_kernel<<<4, 256, 0, stream>>>(Wv, Wv_b, 4096);
  cast_kernel<<<4, 256, 0, stream>>>(Wk, Wk_b, 4096);
  cast_kernel<<<4, 256, 0, stream>>>(Wq, Wq_b, 4096);
  cast_kernel<<<256, 256, 0, stream>>>(Wo, Wo_b, 262144);
  cast_kernel<<<1024, 256, 0, stream>>>(W1, W1_b, 1048576);
  cast_kernel<<<1024, 256, 0, stream>>>(W2, W2_b, 1048576);
  onehot_kernel<<<512, 256, 0, stream>>>(pi, I_mat, ohW, ohb, onehot);

  dim3 gp(4096, 1);
  proj_gemm<false><<<gp, 256, 0, stream>>>(value,  Wv_b, nullptr, v_p, 262144, 64, 64);
  proj_gemm<false><<<gp, 256, 0, stream>>>(key_in, Wk_b, nullptr, k_p, 262144, 64, 64);
  proj_gemm<true ><<<gp, 256, 0, stream>>>(query,  Wq_b, onehot,  q_p, 262144, 64, 64);

  dim3 ga(8, 8, 64);
  attn_kernel<<<ga, 256, 0, stream>>>(q_p, k_p, v_p, attn_o);

  // Wo: (32768x512) = attn_o @ Wo + bo -> bf16 x_b
  dim3 gwo(256, 4);
  gemm128<false, true, false><<<gwo, 256, 0, stream>>>(attn_o, 512, Wo_b, 512, bo, x_b, 512, 32768, 512, 512);
  // LN1 in place on x_b, residual = query + onehot
  ln_kernel<true, false, true, true><<<8192, 256, 0, stream>>>(x_b, query, onehot, g1, b1, x_b);

  // FFN split over 2 column chunks of 1024; split-K accumulate into d_out f32
  for (int c = 0; c < 2; ++c) {
    dim3 gf1(256, 8);
    gemm128<true, true, false><<<gf1, 256, 0, stream>>>(
        x_b, 512, W1_b + c * 1024, 2048, bf1 + c * 1024, ff1c, 1024, 32768, 1024, 512);
    dim3 gf2(256, 4);
    if (c == 0)
      gemm128<false, false, false><<<gf2, 256, 0, stream>>>(
          ff1c, 1024, W2_b + (size_t)c * 1024 * 512, 512, bf2, (float*)d_out, 512, 32768, 512, 1024);
    else
      gemm128<false, false, true><<<gf2, 256, 0, stream>>>(
          ff1c, 1024, W2_b + (size_t)c * 1024 * 512, 512, bf2, (float*)d_out, 512, 32768, 512, 1024);
  }
  // LN2: X = d_out f32, R = x_b bf16 -> d_out in place
  ln_kernel<false, true, false, false><<<8192, 256, 0, stream>>>(d_out, x_b, nullptr, g2, b2, d_out);
}

// Round 3
// 633.170 us; speedup vs baseline: 1.6867x; 1.6867x over previous
//
#include <hip/hip_runtime.h>

typedef __attribute__((ext_vector_type(8))) short s16x8;
typedef __attribute__((ext_vector_type(4))) float f32x4;

#define TN 288

__device__ __forceinline__ unsigned short f2bf(float f) {
  union { float f; unsigned u; } v; v.f = f;
  unsigned r = v.u + 0x7fffu + ((v.u >> 16) & 1u);
  return (unsigned short)(r >> 16);
}
__device__ __forceinline__ float bf2f(unsigned short u) {
  union { float f; unsigned u; } v; v.u = ((unsigned)u) << 16;
  return v.f;
}

__device__ __forceinline__ void async_copy16(unsigned short* lds, const unsigned short* g) {
  __builtin_amdgcn_global_load_lds(
      (const __attribute__((address_space(1))) unsigned int*)g,
      (__attribute__((address_space(3))) unsigned int*)lds, 16, 0, 0);
}

// ---------------- f32 -> bf16 cast (n % 4 == 0) ----------------
__global__ __launch_bounds__(256) void cast_kernel(const float* __restrict__ in,
    unsigned short* __restrict__ out, long n) {
  for (long i = ((long)blockIdx.x * 256 + threadIdx.x) * 4; i < n;
       i += (long)gridDim.x * 1024) {
    float4 f = *(const float4*)(in + i);
    unsigned lo = (unsigned)f2bf(f.x) | ((unsigned)f2bf(f.y) << 16);
    unsigned hi = (unsigned)f2bf(f.z) | ((unsigned)f2bf(f.w) << 16);
    *(uint2*)(out + i) = make_uint2(lo, hi);
  }
}

// ---------------- pack W (f32 row-major KxN) -> MFMA-frag layout ----------
// out[((kb/32)*(N/16)+n16)*512 + lg*128 + lr*8 + j] = bf16(W[kb+lg*8+j][n16*16+lr])
__global__ __launch_bounds__(256) void pack_b(const float* __restrict__ W,
    unsigned short* __restrict__ out, int N, long total8) {
  long t = (long)blockIdx.x * 256 + threadIdx.x;
  if (t >= total8) return;
  int lr = (int)(t & 15);
  int lg = (int)((t >> 4) & 3);
  long g6 = t >> 6;
  int nt = N >> 4;
  int n16 = (int)(g6 % nt);
  int kb = (int)(g6 / nt) << 5;
  int k = kb + lg * 8;
  int col = n16 * 16 + lr;
  s16x8 v;
#pragma unroll
  for (int j = 0; j < 8; ++j) v[j] = (short)f2bf(W[(size_t)(k + j) * N + col]);
  *(s16x8*)(out + t * 8) = v;
}

// ---------------- onehot = I_mat[(i+t)%TN] @ oh_W + oh_b ----------------
__global__ __launch_bounds__(256) void onehot_kernel(const int* __restrict__ pi,
    const float* __restrict__ I_mat, const float* __restrict__ ohW,
    const float* __restrict__ ohb, float* __restrict__ onehot) {
  int t = blockIdx.x;
  int r = (pi[0] + t) % TN;
  int e = threadIdx.x;
  float acc0 = ohb[e], acc1 = ohb[e + 256];
  const float* Ir = I_mat + (size_t)r * TN;
  for (int j = 0; j < TN; ++j) {
    float iv = Ir[j];
    acc0 += iv * ohW[(size_t)j * 512 + e];
    acc1 += iv * ohW[(size_t)j * 512 + e + 256];
  }
  onehot[(size_t)t * 512 + e] = acc0;
  onehot[(size_t)t * 512 + e + 256] = acc1;
}

// ---------------- projection GEMM: C(bf16) = A(f32 [+onehot]) @ B(bf16) ----
template<bool QIN>
__global__ __launch_bounds__(256) void proj_gemm(const float* __restrict__ A,
    const unsigned short* __restrict__ B, const float* __restrict__ onehot,
    unsigned short* __restrict__ C, int M, int N, int K) {
  __shared__ unsigned short As[64][40];
  __shared__ unsigned short Bs[64][40];   // Bs[col][k]
  const int m0 = blockIdx.x * 64, n0 = blockIdx.y * 64;
  const int tid = threadIdx.x, w = tid >> 6, l = tid & 63, lr = l & 15, lg = l >> 4;
  const int wr = (w >> 1) * 32, wc = (w & 1) * 32;
  const int aRow = (tid * 8) >> 5, aK = (tid * 8) & 31;
  const int bK = (tid * 8) >> 6, bCol = (tid * 8) & 63;
  f32x4 acc[2][2] = {};
  for (int kb = 0; kb < K; kb += 32) {
    size_t fl = (size_t)(m0 + aRow) * K + kb + aK;
    float4 f0 = *(const float4*)(A + fl);
    float4 f1 = *(const float4*)(A + fl + 4);
    if (QIN) {
      const float* oh = onehot + (fl & 262143);
      float4 o0 = *(const float4*)(oh);
      float4 o1 = *(const float4*)(oh + 4);
      f0.x += o0.x; f0.y += o0.y; f0.z += o0.z; f0.w += o0.w;
      f1.x += o1.x; f1.y += o1.y; f1.z += o1.z; f1.w += o1.w;
    }
    s16x8 av;
    av[0] = (short)f2bf(f0.x); av[1] = (short)f2bf(f0.y);
    av[2] = (short)f2bf(f0.z); av[3] = (short)f2bf(f0.w);
    av[4] = (short)f2bf(f1.x); av[5] = (short)f2bf(f1.y);
    av[6] = (short)f2bf(f1.z); av[7] = (short)f2bf(f1.w);
    *(s16x8*)&As[aRow][aK] = av;
    s16x8 bv = *(const s16x8*)(B + (size_t)(kb + bK) * N + n0 + bCol);
#pragma unroll
    for (int j = 0; j < 8; ++j) Bs[bCol + j][bK] = (unsigned short)bv[j];
    __syncthreads();
    s16x8 af0 = *(const s16x8*)&As[wr + lr][lg * 8];
    s16x8 af1 = *(const s16x8*)&As[wr + 16 + lr][lg * 8];
    s16x8 bf0 = *(const s16x8*)&Bs[wc + lr][lg * 8];
    s16x8 bf1 = *(const s16x8*)&Bs[wc + 16 + lr][lg * 8];
    acc[0][0] = __builtin_amdgcn_mfma_f32_16x16x32_bf16(af0, bf0, acc[0][0], 0, 0, 0);
    acc[0][1] = __builtin_amdgcn_mfma_f32_16x16x32_bf16(af0, bf1, acc[0][1], 0, 0, 0);
    acc[1][0] = __builtin_amdgcn_mfma_f32_16x16x32_bf16(af1, bf0, acc[1][0], 0, 0, 0);
    acc[1][1] = __builtin_amdgcn_mfma_f32_16x16x32_bf16(af1, bf1, acc[1][1], 0, 0, 0);
    __syncthreads();
  }
#pragma unroll
  for (int fi = 0; fi < 2; ++fi)
#pragma unroll
    for (int fj = 0; fj < 2; ++fj)
#pragma unroll
      for (int r = 0; r < 4; ++r) {
        int row = m0 + wr + fi * 16 + lg * 4 + r;
        int col = n0 + wc + fj * 16 + lr;
        C[(size_t)row * N + col] = f2bf(acc[fi][fj][r]);
      }
}

// ---------------- big GEMM: A bf16 via global_load_lds (swizzled), B packed
// BM=BN=128, BK=32, 4 waves 2x2; per-wave 64x64 = 4x4 frags of 16x16x32
template<bool RELU, bool OUTBF, bool ACC>
__global__ __launch_bounds__(256) void gemmF(
    const unsigned short* __restrict__ A, int lda,
    const unsigned short* __restrict__ Bp, int ldbp, int kOff, int nOff,
    const float* __restrict__ bias, void* __restrict__ Cout, int ldc,
    int M, int K) {
  __shared__ unsigned short As[2][4096];   // [buf][128 rows][32 k] linear, col-swizzled
  const int tid = threadIdx.x, w = tid >> 6, l = tid & 63, lr = l & 15, lg = l >> 4;
  const int m0 = blockIdx.x * 128;
  const int wr = (w >> 1) * 64, wc = (w & 1) * 64;
  // staging: slot s = it*256 + tid -> row s>>2, colblk (s&3)*8, col swizzled by row
  const int srow = tid >> 2, scol = (tid & 3) * 8;
  const int gcol = scol ^ ((srow & 3) << 3);
  const unsigned short* Ag = A + (size_t)(m0 + srow) * lda + gcol;
  const size_t ldaa = (size_t)64 * lda;
  // B fragment base (packed layout)
  const unsigned short* Bg = Bp +
      ((size_t)(nOff >> 4) + blockIdx.y * 8 + (wc >> 4)) * 512 + lg * 128 + lr * 8;
  const size_t bks = (size_t)ldbp * 512;

  f32x4 acc[4][4] = {};
  const int rdswz = (lr & 3) << 3;
  s16x8 bnext[4];

  // prologue: stage kb=0 into buf0, preload B(0)
#pragma unroll
  for (int it = 0; it < 2; ++it)
    async_copy16(&As[0][(w * 64 + it * 256) * 8], Ag + it * ldaa);
  {
    const unsigned short* p = Bg + ((size_t)(kOff >> 5)) * bks;
#pragma unroll
    for (int fj = 0; fj < 4; ++fj) bnext[fj] = *(const s16x8*)(p + fj * 512);
  }
  __syncthreads();

  int buf = 0;
  for (int kb = 0; kb < K; kb += 32) {
    int kb2 = (kb + 32 < K) ? kb + 32 : 0;
    // async stage next A tile
#pragma unroll
    for (int it = 0; it < 2; ++it)
      async_copy16(&As[buf ^ 1][(w * 64 + it * 256) * 8], Ag + kb2 + it * ldaa);
    s16x8 bcur[4];
#pragma unroll
    for (int fj = 0; fj < 4; ++fj) bcur[fj] = bnext[fj];
    {
      const unsigned short* p = Bg + ((size_t)((kOff + kb2) >> 5)) * bks;
#pragma unroll
      for (int fj = 0; fj < 4; ++fj) bnext[fj] = *(const s16x8*)(p + fj * 512);
    }
    s16x8 af[4];
#pragma unroll
    for (int fi = 0; fi < 4; ++fi)
      af[fi] = *(const s16x8*)&As[buf][(wr + fi * 16 + lr) * 32 + (lg * 8 ^ rdswz)];
#pragma unroll
    for (int fi = 0; fi < 4; ++fi)
#pragma unroll
      for (int fj = 0; fj < 4; ++fj)
        acc[fi][fj] = __builtin_amdgcn_mfma_f32_16x16x32_bf16(af[fi], bcur[fj], acc[fi][fj], 0, 0, 0);
    __syncthreads();   // drains vmcnt: stage(kb2) complete; all waves done with As[buf]
    buf ^= 1;
  }

#pragma unroll
  for (int fj = 0; fj < 4; ++fj) {
    int colL = blockIdx.y * 128 + wc + fj * 16 + lr;
    float bv = ACC ? 0.f : bias[nOff + colL];
#pragma unroll
    for (int fi = 0; fi < 4; ++fi)
#pragma unroll
      for (int r = 0; r < 4; ++r) {
        int row = m0 + wr + fi * 16 + lg * 4 + r;
        size_t ci = (size_t)row * ldc + colL;
        float base = ACC ? ((const float*)Cout)[ci] : bv;
        float v = acc[fi][fj][r] + base;
        if (RELU) v = fmaxf(v, 0.f);
        if (OUTBF) ((unsigned short*)Cout)[ci] = f2bf(v);
        else ((float*)Cout)[ci] = v;
      }
  }
}

// ---------------- flash attention: block = (qt, h, n); 4 waves x 16 q-rows
__global__ __launch_bounds__(256) void attn_kernel(
    const unsigned short* __restrict__ Qp, const unsigned short* __restrict__ Kp,
    const unsigned short* __restrict__ Vp, unsigned short* __restrict__ Out) {
  __shared__ unsigned short KS[128][72];     // K chunk, rows kv, cols d
  __shared__ unsigned short Vt[64][136];     // V chunk transposed, swizzled cols
  __shared__ unsigned short P[4][16][136];   // per-wave P tile
  const int qt = blockIdx.x, h = blockIdx.y, n = blockIdx.z;
  const int tid = threadIdx.x, w = tid >> 6, l = tid & 63, lr = l & 15, lg = l >> 4;
  const float scale = 0.044194173824159216f;  // 1/sqrt(512)

  const int qrow_a = qt * 64 + w * 16 + lr;
  const size_t qbase = (((size_t)(n * 512 + qrow_a)) * 8 + h) * 64;
  s16x8 qf0 = *(const s16x8*)(Qp + qbase + lg * 8);
  s16x8 qf1 = *(const s16x8*)(Qp + qbase + 32 + lg * 8);

  f32x4 oacc[4] = {};
  float m[4], lsum[4];
#pragma unroll
  for (int r = 0; r < 4; ++r) { m[r] = -1e30f; lsum[r] = 0.f; }

  for (int c = 0; c < 4; ++c) {
    __syncthreads();   // prev chunk's PV done reading KS/Vt
    // stage K (vector) and V (transposed, swizzled scalar writes)
#pragma unroll
    for (int it = 0; it < 4; ++it) {
      int idx = tid + it * 256;
      int rr = idx >> 3, dd = (idx & 7) * 8;
      size_t gb = (((size_t)(n * 512 + c * 128 + rr)) * 8 + h) * 64 + dd;
      s16x8 kv = *(const s16x8*)(Kp + gb);
      *(s16x8*)&KS[rr][dd] = kv;
      s16x8 vv = *(const s16x8*)(Vp + gb);
#pragma unroll
      for (int j = 0; j < 8; ++j) {
        int row = dd + j;
        Vt[row][rr ^ (((row >> 3) & 7) << 4)] = (unsigned short)vv[j];
      }
    }
    __syncthreads();

    // S = Q K^T for this chunk (8 frags of 16 kv cols)
    f32x4 sacc[8];
#pragma unroll
    for (int f = 0; f < 8; ++f) {
      s16x8 b0 = *(const s16x8*)&KS[f * 16 + lr][lg * 8];
      s16x8 b1 = *(const s16x8*)&KS[f * 16 + lr][32 + lg * 8];
      f32x4 a = {};
      a = __builtin_amdgcn_mfma_f32_16x16x32_bf16(qf0, b0, a, 0, 0, 0);
      a = __builtin_amdgcn_mfma_f32_16x16x32_bf16(qf1, b1, a, 0, 0, 0);
      sacc[f] = a;
    }

    // online softmax update + P (unnormalized) to LDS
    float fs[4];
#pragma unroll
    for (int r = 0; r < 4; ++r) {
      float cm = -1e30f;
#pragma unroll
      for (int f = 0; f < 8; ++f) cm = fmaxf(cm, sacc[f][r]);
#pragma unroll
      for (int mk = 1; mk < 16; mk <<= 1) cm = fmaxf(cm, __shfl_xor(cm, mk));
      float mn = fmaxf(m[r], cm);
      fs[r] = __expf((m[r] - mn) * scale);
      m[r] = mn;
      float cs = 0.f;
#pragma unroll
      for (int f = 0; f < 8; ++f) {
        float p = __expf((sacc[f][r] - mn) * scale);
        P[w][lg * 4 + r][f * 16 + lr] = f2bf(p);
        cs += p;
      }
#pragma unroll
      for (int mk = 1; mk < 16; mk <<= 1) cs += __shfl_xor(cs, mk);
      lsum[r] = lsum[r] * fs[r] + cs;
    }
#pragma unroll
    for (int fj = 0; fj < 4; ++fj)
#pragma unroll
      for (int r = 0; r < 4; ++r) oacc[fj][r] *= fs[r];

    // wave-private P: wait LDS writes, then PV
    asm volatile("s_waitcnt lgkmcnt(0)" ::: "memory");
    __builtin_amdgcn_sched_barrier(0);
#pragma unroll
    for (int ks = 0; ks < 4; ++ks) {
      s16x8 pa = *(const s16x8*)&P[w][lr][ks * 32 + lg * 8];
#pragma unroll
      for (int fj = 0; fj < 4; ++fj) {
        int vrow = fj * 16 + lr;
        s16x8 bv = *(const s16x8*)&Vt[vrow][(ks * 32 + lg * 8) ^ (((vrow >> 3) & 7) << 4)];
        oacc[fj] = __builtin_amdgcn_mfma_f32_16x16x32_bf16(pa, bv, oacc[fj], 0, 0, 0);
      }
    }
  }

#pragma unroll
  for (int fj = 0; fj < 4; ++fj)
#pragma unroll
    for (int r = 0; r < 4; ++r) {
      int qrow = qt * 64 + w * 16 + lg * 4 + r;
      Out[((size_t)(n * 512 + qrow)) * 512 + h * 64 + fj * 16 + lr] =
          f2bf(oacc[fj][r] / lsum[r]);
    }
}

// ---------------- layernorm: 1 wave per 512-elem row, fused residual ------
template<bool XBF, bool RBF, bool QIN, bool OUTBF>
__global__ __launch_bounds__(256) void ln_kernel(const void* __restrict__ Xv,
    const void* __restrict__ Rv, const float* __restrict__ onehot,
    const float* __restrict__ g, const float* __restrict__ bb,
    void* __restrict__ outv) {
  int row = blockIdx.x * 4 + (threadIdx.x >> 6);
  int l = threadIdx.x & 63;
  size_t base = (size_t)row * 512 + l * 8;
  float v[8];
  if (XBF) {
    s16x8 xv = *(const s16x8*)((const unsigned short*)Xv + base);
#pragma unroll
    for (int j = 0; j < 8; ++j) v[j] = bf2f((unsigned short)xv[j]);
  } else {
    const float* X = (const float*)Xv;
    float4 x0 = *(const float4*)(X + base);
    float4 x1 = *(const float4*)(X + base + 4);
    v[0] = x0.x; v[1] = x0.y; v[2] = x0.z; v[3] = x0.w;
    v[4] = x1.x; v[5] = x1.y; v[6] = x1.z; v[7] = x1.w;
  }
  if (RBF) {
    s16x8 rv = *(const s16x8*)((const unsigned short*)Rv + base);
#pragma unroll
    for (int j = 0; j < 8; ++j) v[j] += bf2f((unsigned short)rv[j]);
  } else {
    const float* R = (const float*)Rv;
    float4 r0 = *(const float4*)(R + base);
    float4 r1 = *(const float4*)(R + base + 4);
    v[0] += r0.x; v[1] += r0.y; v[2] += r0.z; v[3] += r0.w;
    v[4] += r1.x; v[5] += r1.y; v[6] += r1.z; v[7] += r1.w;
  }
  if (QIN) {
    size_t ob = (size_t)(row & 511) * 512 + l * 8;
    float4 o0 = *(const float4*)(onehot + ob);
    float4 o1 = *(const float4*)(onehot + ob + 4);
    v[0] += o0.x; v[1] += o0.y; v[2] += o0.z; v[3] += o0.w;
    v[4] += o1.x; v[5] += o1.y; v[6] += o1.z; v[7] += o1.w;
  }
  float s = 0.f, ss = 0.f;
#pragma unroll
  for (int j = 0; j < 8; ++j) { s += v[j]; ss += v[j] * v[j]; }
#pragma unroll
  for (int mk = 1; mk < 64; mk <<= 1) { s += __shfl_xor(s, mk); ss += __shfl_xor(ss, mk); }
  float mu = s * (1.f / 512.f);
  float inv = rsqrtf(ss * (1.f / 512.f) - mu * mu + 1e-5f);
#pragma unroll
  for (int j = 0; j < 8; ++j) {
    int e = l * 8 + j;
    float y = (v[j] - mu) * inv * g[e] + bb[e];
    if (OUTBF) ((unsigned short*)outv)[base + j] = f2bf(y);
    else ((float*)outv)[base + j] = y;
  }
}

extern "C" void kernel_launch(void* const* d_in, const int* in_sizes, int n_in,
                              void* d_out, int out_size, void* d_ws, size_t ws_size,
                              hipStream_t stream) {
  const float* value  = (const float*)d_in[0];
  const float* key_in = (const float*)d_in[1];
  const float* query  = (const float*)d_in[2];
  const int*   pi     = (const int*)d_in[3];
  const float* I_mat  = (const float*)d_in[4];
  const float* ohW    = (const float*)d_in[5];
  const float* ohb    = (const float*)d_in[6];
  const float* Wv     = (const float*)d_in[7];
  const float* Wk     = (const float*)d_in[8];
  const float* Wq     = (const float*)d_in[9];
  const float* Wo     = (const float*)d_in[10];
  const float* bo     = (const float*)d_in[11];
  const float* g1     = (const float*)d_in[12];
  const float* b1     = (const float*)d_in[13];
  const float* g2     = (const float*)d_in[14];
  const float* b2     = (const float*)d_in[15];
  const float* W1     = (const float*)d_in[16];
  const float* bf1    = (const float*)d_in[17];
  const float* W2     = (const float*)d_in[18];
  const float* bf2    = (const float*)d_in[19];

  char* ws = (char*)d_ws;
  const size_t MB = 1024 * 1024;
  unsigned short* q_p  = (unsigned short*)d_out;      // d_out as scratch
  unsigned short* k_p  = q_p + 16777216;
  unsigned short* v_p    = (unsigned short*)(ws + 0);        // 32MB
  unsigned short* attn_o = (unsigned short*)(ws + 32 * MB);  // 32MB
  unsigned short* x_b    = (unsigned short*)(ws + 64 * MB);  // 32MB
  unsigned short* ff1c   = (unsigned short*)(ws + 0);        // 64MB chunk (aliases v_p/attn_o)
  float*          onehot = (float*)(ws + 96 * MB);           // 1MB
  unsigned short* Wv_b   = (unsigned short*)(ws + 97 * MB);
  unsigned short* Wk_b   = Wv_b + 4096;
  unsigned short* Wq_b   = Wk_b + 4096;
  unsigned short* Wop    = Wq_b + 4096;      // 512KB packed
  unsigned short* W1p    = Wop + 262144;     // 2MB packed
  unsigned short* W2p    = W1p + 1048576;    // 2MB packed

  cast_kernel<<<4, 256, 0, stream>>>(Wv, Wv_b, 4096);
  cast_kernel<<<4, 256, 0, stream>>>(Wk, Wk_b, 4096);
  cast_kernel<<<4, 256, 0, stream>>>(Wq, Wq_b, 4096);
  pack_b<<<128, 256, 0, stream>>>(Wo, Wop, 512, 32768);
  pack_b<<<512, 256, 0, stream>>>(W1, W1p, 2048, 131072);
  pack_b<<<512, 256, 0, stream>>>(W2, W2p, 512, 131072);
  onehot_kernel<<<512, 256, 0, stream>>>(pi, I_mat, ohW, ohb, onehot);

  dim3 gp(4096, 1);
  proj_gemm<false><<<gp, 256, 0, stream>>>(value,  Wv_b, nullptr, v_p, 262144, 64, 64);
  proj_gemm<false><<<gp, 256, 0, stream>>>(key_in, Wk_b, nullptr, k_p, 262144, 64, 64);
  proj_gemm<true ><<<gp, 256, 0, stream>>>(query,  Wq_b, onehot,  q_p, 262144, 64, 64);

  dim3 ga(8, 8, 64);
  attn_kernel<<<ga, 256, 0, stream>>>(q_p, k_p, v_p, attn_o);

  // Wo: x_b(bf16) = attn_o @ Wo + bo
  dim3 gwo(256, 4);
  gemmF<false, true, false><<<gwo, 256, 0, stream>>>(
      attn_o, 512, Wop, 32, 0, 0, bo, x_b, 512, 32768, 512);
  // LN1 in place on x_b, residual = query + onehot
  ln_kernel<true, false, true, true><<<8192, 256, 0, stream>>>(x_b, query, onehot, g1, b1, x_b);

  // FFN in 2 column chunks of 1024 with split-K accumulation into d_out f32
  for (int c = 0; c < 2; ++c) {
    dim3 gf1(256, 8);
    gemmF<true, true, false><<<gf1, 256, 0, stream>>>(
        x_b, 512, W1p, 128, 0, c * 1024, bf1, ff1c, 1024, 32768, 512);
    dim3 gf2(256, 4);
    if (c == 0)
      gemmF<false, false, false><<<gf2, 256, 0, stream>>>(
          ff1c, 1024, W2p, 32, c * 1024, 0, bf2, (float*)d_out, 512, 32768, 1024);
    else
      gemmF<false, false, true><<<gf2, 256, 0, stream>>>(
          ff1c, 1024, W2p, 32, c * 1024, 0, bf2, (float*)d_out, 512, 32768, 1024);
  }
  // LN2: X = d_out f32, R = x_b bf16 -> d_out in place
  ln_kernel<false, true, false, false><<<8192, 256, 0, stream>>>(d_out, x_b, nullptr, g2, b2, d_out);
}

// Round 4
// 568.319 us; speedup vs baseline: 1.8792x; 1.1141x over previous
//
#include <hip/hip_runtime.h>

typedef __attribute__((ext_vector_type(8))) short s16x8;
typedef __attribute__((ext_vector_type(4))) float f32x4;
typedef __attribute__((ext_vector_type(4))) unsigned int u32x4;

#define TN 288

__device__ __forceinline__ unsigned short f2bf(float f) {
  union { float f; unsigned u; } v; v.f = f;
  unsigned r = v.u + 0x7fffu + ((v.u >> 16) & 1u);
  return (unsigned short)(r >> 16);
}
__device__ __forceinline__ float bf2f(unsigned short u) {
  union { float f; unsigned u; } v; v.u = ((unsigned)u) << 16;
  return v.f;
}
__device__ __forceinline__ unsigned lds_addr(const void* p) {
  return (unsigned)(unsigned long long)(const __attribute__((address_space(3))) char*)p;
}

__device__ __forceinline__ void async_copy16(unsigned short* lds, const unsigned short* g) {
  __builtin_amdgcn_global_load_lds(
      (const __attribute__((address_space(1))) unsigned int*)g,
      (__attribute__((address_space(3))) unsigned int*)lds, 16, 0, 0);
}

// ---------------- f32 -> bf16 cast with scale (n % 4 == 0) ----------------
__global__ __launch_bounds__(256) void cast_kernel(const float* __restrict__ in,
    unsigned short* __restrict__ out, long n, float sc) {
  for (long i = ((long)blockIdx.x * 256 + threadIdx.x) * 4; i < n;
       i += (long)gridDim.x * 1024) {
    float4 f = *(const float4*)(in + i);
    unsigned lo = (unsigned)f2bf(f.x * sc) | ((unsigned)f2bf(f.y * sc) << 16);
    unsigned hi = (unsigned)f2bf(f.z * sc) | ((unsigned)f2bf(f.w * sc) << 16);
    *(uint2*)(out + i) = make_uint2(lo, hi);
  }
}

// ---------------- pack W (f32 row-major KxN) -> MFMA-frag layout ----------
__global__ __launch_bounds__(256) void pack_b(const float* __restrict__ W,
    unsigned short* __restrict__ out, int N, long total8) {
  long t = (long)blockIdx.x * 256 + threadIdx.x;
  if (t >= total8) return;
  int lr = (int)(t & 15);
  int lg = (int)((t >> 4) & 3);
  long g6 = t >> 6;
  int nt = N >> 4;
  int n16 = (int)(g6 % nt);
  int kb = (int)(g6 / nt) << 5;
  int k = kb + lg * 8;
  int col = n16 * 16 + lr;
  s16x8 v;
#pragma unroll
  for (int j = 0; j < 8; ++j) v[j] = (short)f2bf(W[(size_t)(k + j) * N + col]);
  *(s16x8*)(out + t * 8) = v;
}

// ---------------- onehot = I_mat[(i+t)%TN] @ oh_W + oh_b ----------------
__global__ __launch_bounds__(256) void onehot_kernel(const int* __restrict__ pi,
    const float* __restrict__ I_mat, const float* __restrict__ ohW,
    const float* __restrict__ ohb, float* __restrict__ onehot) {
  int t = blockIdx.x;
  int r = (pi[0] + t) % TN;
  int e = threadIdx.x;
  float acc0 = ohb[e], acc1 = ohb[e + 256];
  const float* Ir = I_mat + (size_t)r * TN;
  for (int j = 0; j < TN; ++j) {
    float iv = Ir[j];
    acc0 += iv * ohW[(size_t)j * 512 + e];
    acc1 += iv * ohW[(size_t)j * 512 + e + 256];
  }
  onehot[(size_t)t * 512 + e] = acc0;
  onehot[(size_t)t * 512 + e + 256] = acc1;
}

// ---------------- projection GEMM: C(bf16) = A(f32 [+onehot]) @ B(bf16) ----
template<bool QIN>
__global__ __launch_bounds__(256) void proj_gemm(const float* __restrict__ A,
    const unsigned short* __restrict__ B, const float* __restrict__ onehot,
    unsigned short* __restrict__ C, int M, int N, int K) {
  __shared__ unsigned short As[64][40];
  __shared__ unsigned short Bs[64][40];   // Bs[col][k]
  const int m0 = blockIdx.x * 64, n0 = blockIdx.y * 64;
  const int tid = threadIdx.x, w = tid >> 6, l = tid & 63, lr = l & 15, lg = l >> 4;
  const int wr = (w >> 1) * 32, wc = (w & 1) * 32;
  const int aRow = (tid * 8) >> 5, aK = (tid * 8) & 31;
  const int bK = (tid * 8) >> 6, bCol = (tid * 8) & 63;
  f32x4 acc[2][2] = {};
  for (int kb = 0; kb < K; kb += 32) {
    size_t fl = (size_t)(m0 + aRow) * K + kb + aK;
    float4 f0 = *(const float4*)(A + fl);
    float4 f1 = *(const float4*)(A + fl + 4);
    if (QIN) {
      const float* oh = onehot + (fl & 262143);
      float4 o0 = *(const float4*)(oh);
      float4 o1 = *(const float4*)(oh + 4);
      f0.x += o0.x; f0.y += o0.y; f0.z += o0.z; f0.w += o0.w;
      f1.x += o1.x; f1.y += o1.y; f1.z += o1.z; f1.w += o1.w;
    }
    s16x8 av;
    av[0] = (short)f2bf(f0.x); av[1] = (short)f2bf(f0.y);
    av[2] = (short)f2bf(f0.z); av[3] = (short)f2bf(f0.w);
    av[4] = (short)f2bf(f1.x); av[5] = (short)f2bf(f1.y);
    av[6] = (short)f2bf(f1.z); av[7] = (short)f2bf(f1.w);
    *(s16x8*)&As[aRow][aK] = av;
    s16x8 bv = *(const s16x8*)(B + (size_t)(kb + bK) * N + n0 + bCol);
#pragma unroll
    for (int j = 0; j < 8; ++j) Bs[bCol + j][bK] = (unsigned short)bv[j];
    __syncthreads();
    s16x8 af0 = *(const s16x8*)&As[wr + lr][lg * 8];
    s16x8 af1 = *(const s16x8*)&As[wr + 16 + lr][lg * 8];
    s16x8 bf0 = *(const s16x8*)&Bs[wc + lr][lg * 8];
    s16x8 bf1 = *(const s16x8*)&Bs[wc + 16 + lr][lg * 8];
    acc[0][0] = __builtin_amdgcn_mfma_f32_16x16x32_bf16(af0, bf0, acc[0][0], 0, 0, 0);
    acc[0][1] = __builtin_amdgcn_mfma_f32_16x16x32_bf16(af0, bf1, acc[0][1], 0, 0, 0);
    acc[1][0] = __builtin_amdgcn_mfma_f32_16x16x32_bf16(af1, bf0, acc[1][0], 0, 0, 0);
    acc[1][1] = __builtin_amdgcn_mfma_f32_16x16x32_bf16(af1, bf1, acc[1][1], 0, 0, 0);
    __syncthreads();
  }
#pragma unroll
  for (int fi = 0; fi < 2; ++fi)
#pragma unroll
    for (int fj = 0; fj < 2; ++fj)
#pragma unroll
      for (int r = 0; r < 4; ++r) {
        int row = m0 + wr + fi * 16 + lg * 4 + r;
        int col = n0 + wc + fj * 16 + lr;
        C[(size_t)row * N + col] = f2bf(acc[fi][fj][r]);
      }
}

// ---------------- big GEMM: A bf16 via global_load_lds (swizzled), B packed
template<bool RELU, bool OUTBF>
__global__ __launch_bounds__(256) void gemmF(
    const unsigned short* __restrict__ A, int lda,
    const unsigned short* __restrict__ Bp, int ldbp, int kOff, int nOff,
    const float* __restrict__ bias, void* __restrict__ Cout, int ldc,
    int M, int K) {
  __shared__ unsigned short As[2][4096];   // [buf][128 rows][32 k] linear, col-swizzled
  const int tid = threadIdx.x, w = tid >> 6, l = tid & 63, lr = l & 15, lg = l >> 4;
  const int m0 = blockIdx.x * 128;
  const int wr = (w >> 1) * 64, wc = (w & 1) * 64;
  const int srow = tid >> 2, scol = (tid & 3) * 8;
  const int gcol = scol ^ ((srow & 3) << 3);
  const unsigned short* Ag = A + (size_t)(m0 + srow) * lda + gcol;
  const size_t ldaa = (size_t)64 * lda;
  const unsigned short* Bg = Bp +
      ((size_t)(nOff >> 4) + blockIdx.y * 8 + (wc >> 4)) * 512 + lg * 128 + lr * 8;
  const size_t bks = (size_t)ldbp * 512;

  f32x4 acc[4][4] = {};
  const int rdswz = (lr & 3) << 3;
  s16x8 bnext[4];

#pragma unroll
  for (int it = 0; it < 2; ++it)
    async_copy16(&As[0][(w * 64 + it * 256) * 8], Ag + it * ldaa);
  {
    const unsigned short* p = Bg + ((size_t)(kOff >> 5)) * bks;
#pragma unroll
    for (int fj = 0; fj < 4; ++fj) bnext[fj] = *(const s16x8*)(p + fj * 512);
  }
  __syncthreads();

  int buf = 0;
  for (int kb = 0; kb < K; kb += 32) {
    int kb2 = (kb + 32 < K) ? kb + 32 : 0;
#pragma unroll
    for (int it = 0; it < 2; ++it)
      async_copy16(&As[buf ^ 1][(w * 64 + it * 256) * 8], Ag + kb2 + it * ldaa);
    s16x8 bcur[4];
#pragma unroll
    for (int fj = 0; fj < 4; ++fj) bcur[fj] = bnext[fj];
    {
      const unsigned short* p = Bg + ((size_t)((kOff + kb2) >> 5)) * bks;
#pragma unroll
      for (int fj = 0; fj < 4; ++fj) bnext[fj] = *(const s16x8*)(p + fj * 512);
    }
    s16x8 af[4];
#pragma unroll
    for (int fi = 0; fi < 4; ++fi)
      af[fi] = *(const s16x8*)&As[buf][(wr + fi * 16 + lr) * 32 + (lg * 8 ^ rdswz)];
#pragma unroll
    for (int fi = 0; fi < 4; ++fi)
#pragma unroll
      for (int fj = 0; fj < 4; ++fj)
        acc[fi][fj] = __builtin_amdgcn_mfma_f32_16x16x32_bf16(af[fi], bcur[fj], acc[fi][fj], 0, 0, 0);
    __syncthreads();
    buf ^= 1;
  }

#pragma unroll
  for (int fj = 0; fj < 4; ++fj) {
    int colL = blockIdx.y * 128 + wc + fj * 16 + lr;
    float bv = bias[nOff + colL];
#pragma unroll
    for (int fi = 0; fi < 4; ++fi)
#pragma unroll
      for (int r = 0; r < 4; ++r) {
        int row = m0 + wr + fi * 16 + lg * 4 + r;
        size_t ci = (size_t)row * ldc + colL;
        float v = acc[fi][fj][r] + bv;
        if (RELU) v = fmaxf(v, 0.f);
        if (OUTBF) ((unsigned short*)Cout)[ci] = f2bf(v);
        else ((float*)Cout)[ci] = v;
      }
  }
}

// ---------------- flash attention; 1D grid, XCD-grouped: bid = qt*512+(h+8n)
__global__ __launch_bounds__(256) void attn_kernel(
    const unsigned short* __restrict__ Qp, const unsigned short* __restrict__ Kp,
    const unsigned short* __restrict__ Vp, unsigned short* __restrict__ Out) {
  __shared__ unsigned short KS[128][72];
  __shared__ unsigned short Vt[64][136];
  __shared__ unsigned short P[4][16][136];
  const int bid = blockIdx.x;
  const int qt = bid >> 9, g = bid & 511, h = g & 7, n = g >> 3;
  const int tid = threadIdx.x, w = tid >> 6, l = tid & 63, lr = l & 15, lg = l >> 4;

  const int qrow_a = qt * 64 + w * 16 + lr;
  const size_t qbase = (((size_t)(n * 512 + qrow_a)) * 8 + h) * 64;
  s16x8 qf0 = *(const s16x8*)(Qp + qbase + lg * 8);
  s16x8 qf1 = *(const s16x8*)(Qp + qbase + 32 + lg * 8);

  f32x4 oacc[4] = {};
  float m[4], lsum[4];
#pragma unroll
  for (int r = 0; r < 4; ++r) { m[r] = -1e30f; lsum[r] = 0.f; }

  for (int c = 0; c < 4; ++c) {
    __syncthreads();   // prev chunk's PV done reading KS/Vt
#pragma unroll
    for (int it = 0; it < 4; ++it) {
      int idx = tid + it * 256;
      int rr = idx >> 3, dd = (idx & 7) * 8;
      size_t gb = (((size_t)(n * 512 + c * 128 + rr)) * 8 + h) * 64 + dd;
      s16x8 kv = *(const s16x8*)(Kp + gb);
      *(s16x8*)&KS[rr][dd] = kv;
      s16x8 vv = *(const s16x8*)(Vp + gb);
      // V transposed store: rows dd..dd+7, col = rr ^ swz(dd); imm-offset chain
      unsigned va = lds_addr(&Vt[dd][rr ^ ((dd >> 3) << 4)]);
      u32x4 uw = (u32x4)vv;
#pragma unroll
      for (int jj = 0; jj < 4; ++jj) {
        asm volatile("ds_write_b16 %0, %1 offset:%2"
                     :: "v"(va), "v"(uw[jj]), "i"(jj * 544) : "memory");
        asm volatile("ds_write_b16_d16_hi %0, %1 offset:%2"
                     :: "v"(va), "v"(uw[jj]), "i"(jj * 544 + 272) : "memory");
      }
    }
    __syncthreads();

    // S = Q K^T (scale pre-folded into Wq)
    f32x4 sacc[8];
    __builtin_amdgcn_s_setprio(1);
#pragma unroll
    for (int f = 0; f < 8; ++f) {
      s16x8 b0 = *(const s16x8*)&KS[f * 16 + lr][lg * 8];
      s16x8 b1 = *(const s16x8*)&KS[f * 16 + lr][32 + lg * 8];
      f32x4 a = {};
      a = __builtin_amdgcn_mfma_f32_16x16x32_bf16(qf0, b0, a, 0, 0, 0);
      a = __builtin_amdgcn_mfma_f32_16x16x32_bf16(qf1, b1, a, 0, 0, 0);
      sacc[f] = a;
    }
    __builtin_amdgcn_s_setprio(0);

    // online softmax update; P stored bf16-RTZ via d16_hi writes
    float fs[4];
#pragma unroll
    for (int r = 0; r < 4; ++r) {
      float cm = sacc[0][r];
#pragma unroll
      for (int f = 1; f < 8; ++f) cm = fmaxf(cm, sacc[f][r]);
#pragma unroll
      for (int mk = 1; mk < 16; mk <<= 1) cm = fmaxf(cm, __shfl_xor(cm, mk));
      float mn = fmaxf(m[r], cm);
      fs[r] = __expf(m[r] - mn);
      m[r] = mn;
      unsigned pa = lds_addr(&P[w][lg * 4 + r][lr]);
      float cs = 0.f;
#pragma unroll
      for (int f = 0; f < 8; ++f) {
        float p = __expf(sacc[f][r] - mn);
        asm volatile("ds_write_b16_d16_hi %0, %1 offset:%2"
                     :: "v"(pa), "v"(p), "i"(f * 32) : "memory");
        cs += p;
      }
#pragma unroll
      for (int mk = 1; mk < 16; mk <<= 1) cs += __shfl_xor(cs, mk);
      lsum[r] = lsum[r] * fs[r] + cs;
    }
#pragma unroll
    for (int fj = 0; fj < 4; ++fj)
#pragma unroll
      for (int r = 0; r < 4; ++r) oacc[fj][r] *= fs[r];

    // wave-private P: wait LDS writes, then PV
    asm volatile("s_waitcnt lgkmcnt(0)" ::: "memory");
    __builtin_amdgcn_sched_barrier(0);
    __builtin_amdgcn_s_setprio(1);
#pragma unroll
    for (int ks = 0; ks < 4; ++ks) {
      s16x8 pa = *(const s16x8*)&P[w][lr][ks * 32 + lg * 8];
#pragma unroll
      for (int fj = 0; fj < 4; ++fj) {
        int vrow = fj * 16 + lr;
        s16x8 bv = *(const s16x8*)&Vt[vrow][(ks * 32 + lg * 8) ^ (((vrow >> 3) & 7) << 4)];
        oacc[fj] = __builtin_amdgcn_mfma_f32_16x16x32_bf16(pa, bv, oacc[fj], 0, 0, 0);
      }
    }
    __builtin_amdgcn_s_setprio(0);
  }

#pragma unroll
  for (int fj = 0; fj < 4; ++fj)
#pragma unroll
    for (int r = 0; r < 4; ++r) {
      int qrow = qt * 64 + w * 16 + lg * 4 + r;
      Out[((size_t)(n * 512 + qrow)) * 512 + h * 64 + fj * 16 + lr] =
          f2bf(oacc[fj][r] / lsum[r]);
    }
}

// ---------------- layernorm: 1 wave per 512-elem row, fused residual ------
template<bool XBF, bool RBF, bool QIN, bool OUTBF>
__global__ __launch_bounds__(256) void ln_kernel(const void* __restrict__ Xv,
    const void* __restrict__ Rv, const float* __restrict__ onehot,
    const float* __restrict__ g, const float* __restrict__ bb,
    void* __restrict__ outv) {
  int row = blockIdx.x * 4 + (threadIdx.x >> 6);
  int l = threadIdx.x & 63;
  size_t base = (size_t)row * 512 + l * 8;
  float v[8];
  if (XBF) {
    s16x8 xv = *(const s16x8*)((const unsigned short*)Xv + base);
#pragma unroll
    for (int j = 0; j < 8; ++j) v[j] = bf2f((unsigned short)xv[j]);
  } else {
    const float* X = (const float*)Xv;
    float4 x0 = *(const float4*)(X + base);
    float4 x1 = *(const float4*)(X + base + 4);
    v[0] = x0.x; v[1] = x0.y; v[2] = x0.z; v[3] = x0.w;
    v[4] = x1.x; v[5] = x1.y; v[6] = x1.z; v[7] = x1.w;
  }
  if (RBF) {
    s16x8 rv = *(const s16x8*)((const unsigned short*)Rv + base);
#pragma unroll
    for (int j = 0; j < 8; ++j) v[j] += bf2f((unsigned short)rv[j]);
  } else {
    const float* R = (const float*)Rv;
    float4 r0 = *(const float4*)(R + base);
    float4 r1 = *(const float4*)(R + base + 4);
    v[0] += r0.x; v[1] += r0.y; v[2] += r0.z; v[3] += r0.w;
    v[4] += r1.x; v[5] += r1.y; v[6] += r1.z; v[7] += r1.w;
  }
  if (QIN) {
    size_t ob = (size_t)(row & 511) * 512 + l * 8;
    float4 o0 = *(const float4*)(onehot + ob);
    float4 o1 = *(const float4*)(onehot + ob + 4);
    v[0] += o0.x; v[1] += o0.y; v[2] += o0.z; v[3] += o0.w;
    v[4] += o1.x; v[5] += o1.y; v[6] += o1.z; v[7] += o1.w;
  }
  float s = 0.f, ss = 0.f;
#pragma unroll
  for (int j = 0; j < 8; ++j) { s += v[j]; ss += v[j] * v[j]; }
#pragma unroll
  for (int mk = 1; mk < 64; mk <<= 1) { s += __shfl_xor(s, mk); ss += __shfl_xor(ss, mk); }
  float mu = s * (1.f / 512.f);
  float inv = rsqrtf(ss * (1.f / 512.f) - mu * mu + 1e-5f);
#pragma unroll
  for (int j = 0; j < 8; ++j) {
    int e = l * 8 + j;
    float y = (v[j] - mu) * inv * g[e] + bb[e];
    if (OUTBF) ((unsigned short*)outv)[base + j] = f2bf(y);
    else ((float*)outv)[base + j] = y;
  }
}

extern "C" void kernel_launch(void* const* d_in, const int* in_sizes, int n_in,
                              void* d_out, int out_size, void* d_ws, size_t ws_size,
                              hipStream_t stream) {
  const float* value  = (const float*)d_in[0];
  const float* key_in = (const float*)d_in[1];
  const float* query  = (const float*)d_in[2];
  const int*   pi     = (const int*)d_in[3];
  const float* I_mat  = (const float*)d_in[4];
  const float* ohW    = (const float*)d_in[5];
  const float* ohb    = (const float*)d_in[6];
  const float* Wv     = (const float*)d_in[7];
  const float* Wk     = (const float*)d_in[8];
  const float* Wq     = (const float*)d_in[9];
  const float* Wo     = (const float*)d_in[10];
  const float* bo     = (const float*)d_in[11];
  const float* g1     = (const float*)d_in[12];
  const float* b1     = (const float*)d_in[13];
  const float* g2     = (const float*)d_in[14];
  const float* b2     = (const float*)d_in[15];
  const float* W1     = (const float*)d_in[16];
  const float* bf1    = (const float*)d_in[17];
  const float* W2     = (const float*)d_in[18];
  const float* bf2    = (const float*)d_in[19];

  char* ws = (char*)d_ws;
  const size_t MB = 1024 * 1024;
  unsigned short* q_p  = (unsigned short*)d_out;      // d_out as scratch
  unsigned short* k_p  = q_p + 16777216;
  unsigned short* v_p    = (unsigned short*)(ws + 0);        // 32MB
  unsigned short* attn_o = (unsigned short*)(ws + 32 * MB);  // 32MB
  unsigned short* x_b    = (unsigned short*)(ws + 64 * MB);  // 32MB
  unsigned short* ff1h   = (unsigned short*)(ws + 0);        // 64MB half (aliases v_p/attn_o)
  float*          onehot = (float*)(ws + 96 * MB);           // 1MB
  unsigned short* Wv_b   = (unsigned short*)(ws + 97 * MB);
  unsigned short* Wk_b   = Wv_b + 4096;
  unsigned short* Wq_b   = Wk_b + 4096;
  unsigned short* Wop    = Wq_b + 4096;      // 512KB packed
  unsigned short* W1p    = Wop + 262144;     // 2MB packed
  unsigned short* W2p    = W1p + 1048576;    // 2MB packed

  cast_kernel<<<4, 256, 0, stream>>>(Wv, Wv_b, 4096, 1.f);
  cast_kernel<<<4, 256, 0, stream>>>(Wk, Wk_b, 4096, 1.f);
  cast_kernel<<<4, 256, 0, stream>>>(Wq, Wq_b, 4096, 0.044194173824159216f);
  pack_b<<<128, 256, 0, stream>>>(Wo, Wop, 512, 32768);
  pack_b<<<512, 256, 0, stream>>>(W1, W1p, 2048, 131072);
  pack_b<<<512, 256, 0, stream>>>(W2, W2p, 512, 131072);
  onehot_kernel<<<512, 256, 0, stream>>>(pi, I_mat, ohW, ohb, onehot);

  dim3 gp(4096, 1);
  proj_gemm<false><<<gp, 256, 0, stream>>>(value,  Wv_b, nullptr, v_p, 262144, 64, 64);
  proj_gemm<false><<<gp, 256, 0, stream>>>(key_in, Wk_b, nullptr, k_p, 262144, 64, 64);
  proj_gemm<true ><<<gp, 256, 0, stream>>>(query,  Wq_b, onehot,  q_p, 262144, 64, 64);

  attn_kernel<<<4096, 256, 0, stream>>>(q_p, k_p, v_p, attn_o);

  // Wo: x_b(bf16) = attn_o @ Wo + bo
  dim3 gwo(256, 4);
  gemmF<false, true><<<gwo, 256, 0, stream>>>(
      attn_o, 512, Wop, 32, 0, 0, bo, x_b, 512, 32768, 512);
  // LN1 in place on x_b, residual = query + onehot
  ln_kernel<true, false, true, true><<<8192, 256, 0, stream>>>(x_b, query, onehot, g1, b1, x_b);

  // FFN split over 2 row-halves (M=16384 each); no split-K round trip
  for (int hf = 0; hf < 2; ++hf) {
    const unsigned short* xh = x_b + (size_t)hf * 16384 * 512;
    dim3 gf1(128, 16);
    gemmF<true, true><<<gf1, 256, 0, stream>>>(
        xh, 512, W1p, 128, 0, 0, bf1, ff1h, 2048, 16384, 512);
    dim3 gf2(128, 4);
    gemmF<false, false><<<gf2, 256, 0, stream>>>(
        ff1h, 2048, W2p, 32, 0, 0, bf2, (float*)d_out + (size_t)hf * 16384 * 512, 512, 16384, 2048);
  }
  // LN2: X = d_out f32, R = x_b bf16 -> d_out in place
  ln_kernel<false, true, false, false><<<8192, 256, 0, stream>>>(d_out, x_b, nullptr, g2, b2, d_out);
}

// Round 5
// 563.086 us; speedup vs baseline: 1.8967x; 1.0093x over previous
//
#include <hip/hip_runtime.h>

typedef __attribute__((ext_vector_type(8))) short s16x8;
typedef __attribute__((ext_vector_type(4))) float f32x4;
typedef __attribute__((ext_vector_type(4))) unsigned int u32x4;

#define TN 288

__device__ __forceinline__ unsigned short f2bf(float f) {
  union { float f; unsigned u; } v; v.f = f;
  unsigned r = v.u + 0x7fffu + ((v.u >> 16) & 1u);
  return (unsigned short)(r >> 16);
}
__device__ __forceinline__ float bf2f(unsigned short u) {
  union { float f; unsigned u; } v; v.u = ((unsigned)u) << 16;
  return v.f;
}
__device__ __forceinline__ unsigned lds_addr(const void* p) {
  return (unsigned)(unsigned long long)(const __attribute__((address_space(3))) char*)p;
}

__device__ __forceinline__ void async_copy16(unsigned short* lds, const unsigned short* g) {
  __builtin_amdgcn_global_load_lds(
      (const __attribute__((address_space(1))) unsigned int*)g,
      (__attribute__((address_space(3))) unsigned int*)lds, 16, 0, 0);
}

// ---------------- f32 -> bf16 cast with scale (n % 4 == 0) ----------------
__global__ __launch_bounds__(256) void cast_kernel(const float* __restrict__ in,
    unsigned short* __restrict__ out, long n, float sc) {
  for (long i = ((long)blockIdx.x * 256 + threadIdx.x) * 4; i < n;
       i += (long)gridDim.x * 1024) {
    float4 f = *(const float4*)(in + i);
    unsigned lo = (unsigned)f2bf(f.x * sc) | ((unsigned)f2bf(f.y * sc) << 16);
    unsigned hi = (unsigned)f2bf(f.z * sc) | ((unsigned)f2bf(f.w * sc) << 16);
    *(uint2*)(out + i) = make_uint2(lo, hi);
  }
}

// ---------------- pack W (f32 row-major KxN) -> MFMA-frag layout ----------
__global__ __launch_bounds__(256) void pack_b(const float* __restrict__ W,
    unsigned short* __restrict__ out, int N, long total8) {
  long t = (long)blockIdx.x * 256 + threadIdx.x;
  if (t >= total8) return;
  int lr = (int)(t & 15);
  int lg = (int)((t >> 4) & 3);
  long g6 = t >> 6;
  int nt = N >> 4;
  int n16 = (int)(g6 % nt);
  int kb = (int)(g6 / nt) << 5;
  int k = kb + lg * 8;
  int col = n16 * 16 + lr;
  s16x8 v;
#pragma unroll
  for (int j = 0; j < 8; ++j) v[j] = (short)f2bf(W[(size_t)(k + j) * N + col]);
  *(s16x8*)(out + t * 8) = v;
}

// ---------------- onehot = I_mat[(i+t)%TN] @ oh_W + oh_b ----------------
__global__ __launch_bounds__(256) void onehot_kernel(const int* __restrict__ pi,
    const float* __restrict__ I_mat, const float* __restrict__ ohW,
    const float* __restrict__ ohb, float* __restrict__ onehot) {
  int t = blockIdx.x;
  int r = (pi[0] + t) % TN;
  int e = threadIdx.x;
  float acc0 = ohb[e], acc1 = ohb[e + 256];
  const float* Ir = I_mat + (size_t)r * TN;
  for (int j = 0; j < TN; ++j) {
    float iv = Ir[j];
    acc0 += iv * ohW[(size_t)j * 512 + e];
    acc1 += iv * ohW[(size_t)j * 512 + e + 256];
  }
  onehot[(size_t)t * 512 + e] = acc0;
  onehot[(size_t)t * 512 + e + 256] = acc1;
}

// ---------------- projection GEMM: C(bf16) = A(f32 [+onehot]) @ B(bf16) ----
// OUTMODE 0: row-major C[row][col]. OUTMODE 1: V-transposed vT[n][h][d][t]
// (M rows encode ((n*512+t)*8+h), N=64=d; write via LDS bounce).
template<bool QIN, int OUTMODE>
__global__ __launch_bounds__(256) void proj_gemm(const float* __restrict__ A,
    const unsigned short* __restrict__ B, const float* __restrict__ onehot,
    unsigned short* __restrict__ C, int M, int N, int K) {
  __shared__ unsigned short As[64][40];
  __shared__ unsigned short Bs[64][40];   // Bs[col][k]
  __shared__ unsigned short Cs[64][72];   // OUTMODE 1 bounce
  const int m0 = blockIdx.x * 64, n0 = blockIdx.y * 64;
  const int tid = threadIdx.x, w = tid >> 6, l = tid & 63, lr = l & 15, lg = l >> 4;
  const int wr = (w >> 1) * 32, wc = (w & 1) * 32;
  const int aRow = (tid * 8) >> 5, aK = (tid * 8) & 31;
  const int bK = (tid * 8) >> 6, bCol = (tid * 8) & 63;
  f32x4 acc[2][2] = {};
  for (int kb = 0; kb < K; kb += 32) {
    size_t fl = (size_t)(m0 + aRow) * K + kb + aK;
    float4 f0 = *(const float4*)(A + fl);
    float4 f1 = *(const float4*)(A + fl + 4);
    if (QIN) {
      const float* oh = onehot + (fl & 262143);
      float4 o0 = *(const float4*)(oh);
      float4 o1 = *(const float4*)(oh + 4);
      f0.x += o0.x; f0.y += o0.y; f0.z += o0.z; f0.w += o0.w;
      f1.x += o1.x; f1.y += o1.y; f1.z += o1.z; f1.w += o1.w;
    }
    s16x8 av;
    av[0] = (short)f2bf(f0.x); av[1] = (short)f2bf(f0.y);
    av[2] = (short)f2bf(f0.z); av[3] = (short)f2bf(f0.w);
    av[4] = (short)f2bf(f1.x); av[5] = (short)f2bf(f1.y);
    av[6] = (short)f2bf(f1.z); av[7] = (short)f2bf(f1.w);
    *(s16x8*)&As[aRow][aK] = av;
    s16x8 bv = *(const s16x8*)(B + (size_t)(kb + bK) * N + n0 + bCol);
#pragma unroll
    for (int j = 0; j < 8; ++j) Bs[bCol + j][bK] = (unsigned short)bv[j];
    __syncthreads();
    s16x8 af0 = *(const s16x8*)&As[wr + lr][lg * 8];
    s16x8 af1 = *(const s16x8*)&As[wr + 16 + lr][lg * 8];
    s16x8 bf0 = *(const s16x8*)&Bs[wc + lr][lg * 8];
    s16x8 bf1 = *(const s16x8*)&Bs[wc + 16 + lr][lg * 8];
    acc[0][0] = __builtin_amdgcn_mfma_f32_16x16x32_bf16(af0, bf0, acc[0][0], 0, 0, 0);
    acc[0][1] = __builtin_amdgcn_mfma_f32_16x16x32_bf16(af0, bf1, acc[0][1], 0, 0, 0);
    acc[1][0] = __builtin_amdgcn_mfma_f32_16x16x32_bf16(af1, bf0, acc[1][0], 0, 0, 0);
    acc[1][1] = __builtin_amdgcn_mfma_f32_16x16x32_bf16(af1, bf1, acc[1][1], 0, 0, 0);
    __syncthreads();
  }
  if (OUTMODE == 0) {
#pragma unroll
    for (int fi = 0; fi < 2; ++fi)
#pragma unroll
      for (int fj = 0; fj < 2; ++fj)
#pragma unroll
        for (int r = 0; r < 4; ++r) {
          int row = m0 + wr + fi * 16 + lg * 4 + r;
          int col = n0 + wc + fj * 16 + lr;
          C[(size_t)row * N + col] = f2bf(acc[fi][fj][r]);
        }
  } else {
    // bounce through LDS, emit vT[((n*8+h)*64+d)*512 + t]
#pragma unroll
    for (int fi = 0; fi < 2; ++fi)
#pragma unroll
      for (int fj = 0; fj < 2; ++fj)
#pragma unroll
        for (int r = 0; r < 4; ++r)
          Cs[wr + fi * 16 + lg * 4 + r][wc + fj * 16 + lr] = f2bf(acc[fi][fj][r]);
    __syncthreads();
    int nIdx = m0 >> 12, t0 = (m0 >> 3) & 511;
#pragma unroll
    for (int it = 0; it < 2; ++it) {
      int p = tid + it * 256;
      int hh = p >> 6, d = p & 63;
      s16x8 vv;
#pragma unroll
      for (int j = 0; j < 8; ++j) vv[j] = (short)Cs[j * 8 + hh][d];
      *(s16x8*)(C + (((size_t)(nIdx * 8 + hh) * 64 + d) << 9) + t0) = vv;
    }
  }
}

// ---------------- big GEMM: A bf16 via global_load_lds (swizzled), B packed
template<bool RELU, bool OUTBF>
__global__ __launch_bounds__(256) void gemmF(
    const unsigned short* __restrict__ A, int lda,
    const unsigned short* __restrict__ Bp, int ldbp, int kOff, int nOff,
    const float* __restrict__ bias, void* __restrict__ Cout, int ldc,
    int M, int K) {
  __shared__ unsigned short As[2][4096];
  const int tid = threadIdx.x, w = tid >> 6, l = tid & 63, lr = l & 15, lg = l >> 4;
  const int m0 = blockIdx.x * 128;
  const int wr = (w >> 1) * 64, wc = (w & 1) * 64;
  const int srow = tid >> 2, scol = (tid & 3) * 8;
  const int gcol = scol ^ ((srow & 3) << 3);
  const unsigned short* Ag = A + (size_t)(m0 + srow) * lda + gcol;
  const size_t ldaa = (size_t)64 * lda;
  const unsigned short* Bg = Bp +
      ((size_t)(nOff >> 4) + blockIdx.y * 8 + (wc >> 4)) * 512 + lg * 128 + lr * 8;
  const size_t bks = (size_t)ldbp * 512;

  f32x4 acc[4][4] = {};
  const int rdswz = (lr & 3) << 3;
  s16x8 bnext[4];

#pragma unroll
  for (int it = 0; it < 2; ++it)
    async_copy16(&As[0][(w * 64 + it * 256) * 8], Ag + it * ldaa);
  {
    const unsigned short* p = Bg + ((size_t)(kOff >> 5)) * bks;
#pragma unroll
    for (int fj = 0; fj < 4; ++fj) bnext[fj] = *(const s16x8*)(p + fj * 512);
  }
  __syncthreads();

  int buf = 0;
  for (int kb = 0; kb < K; kb += 32) {
    int kb2 = (kb + 32 < K) ? kb + 32 : 0;
#pragma unroll
    for (int it = 0; it < 2; ++it)
      async_copy16(&As[buf ^ 1][(w * 64 + it * 256) * 8], Ag + kb2 + it * ldaa);
    s16x8 bcur[4];
#pragma unroll
    for (int fj = 0; fj < 4; ++fj) bcur[fj] = bnext[fj];
    {
      const unsigned short* p = Bg + ((size_t)((kOff + kb2) >> 5)) * bks;
#pragma unroll
      for (int fj = 0; fj < 4; ++fj) bnext[fj] = *(const s16x8*)(p + fj * 512);
    }
    s16x8 af[4];
#pragma unroll
    for (int fi = 0; fi < 4; ++fi)
      af[fi] = *(const s16x8*)&As[buf][(wr + fi * 16 + lr) * 32 + (lg * 8 ^ rdswz)];
#pragma unroll
    for (int fi = 0; fi < 4; ++fi)
#pragma unroll
      for (int fj = 0; fj < 4; ++fj)
        acc[fi][fj] = __builtin_amdgcn_mfma_f32_16x16x32_bf16(af[fi], bcur[fj], acc[fi][fj], 0, 0, 0);
    __syncthreads();
    buf ^= 1;
  }

#pragma unroll
  for (int fj = 0; fj < 4; ++fj) {
    int colL = blockIdx.y * 128 + wc + fj * 16 + lr;
    float bv = bias[nOff + colL];
#pragma unroll
    for (int fi = 0; fi < 4; ++fi)
#pragma unroll
      for (int r = 0; r < 4; ++r) {
        int row = m0 + wr + fi * 16 + lg * 4 + r;
        size_t ci = (size_t)row * ldc + colL;
        float v = acc[fi][fj][r] + bv;
        if (RELU) v = fmaxf(v, 0.f);
        if (OUTBF) ((unsigned short*)Cout)[ci] = f2bf(v);
        else ((float*)Cout)[ci] = v;
      }
  }
}

// ---------------- flash attention: block = 256 q-rows of one (h,n) --------
// grid 1024: bid = qh*512 + (h + 8n); 4 waves x 4 rowtiles x 16 q-rows.
// K staged in LDS per 128-kv chunk; V read direct from global vT (L2-resident)
// into 16 regs per chunk, shared across rowtiles. Q staged once in LDS.
__global__ __launch_bounds__(256, 2) void attn_kernel(
    const unsigned short* __restrict__ Qp, const unsigned short* __restrict__ Kp,
    const unsigned short* __restrict__ Vt, unsigned short* __restrict__ Out) {
  __shared__ unsigned short QL[256][72];
  __shared__ unsigned short KS[128][72];
  __shared__ unsigned short P[4][16][132];
  const int bid = blockIdx.x;
  const int qh = bid >> 9, g = bid & 511, h = g & 7, n = g >> 3;
  const int tid = threadIdx.x, w = tid >> 6, l = tid & 63, lr = l & 15, lg = l >> 4;
  const int q0 = qh * 256;

  // stage Q: 256 rows x 64
#pragma unroll
  for (int it = 0; it < 8; ++it) {
    int idx = tid + it * 256;
    int rr = idx >> 3, dd = (idx & 7) * 8;
    *(s16x8*)&QL[rr][dd] =
        *(const s16x8*)(Qp + (((size_t)(n * 512 + q0 + rr)) * 8 + h) * 64 + dd);
  }
  const unsigned short* Vb = Vt + ((size_t)(n * 8 + h)) * 32768 + (size_t)lr * 512 + lg * 8;

  f32x4 oacc[4][4] = {};
  float m[4][4], lsum[4][4];
#pragma unroll
  for (int rt = 0; rt < 4; ++rt)
#pragma unroll
    for (int r = 0; r < 4; ++r) { m[rt][r] = -1e30f; lsum[rt][r] = 0.f; }
  s16x8 vreg[16];

  // prologue: stage K(0), load V(0)
#pragma unroll
  for (int it = 0; it < 4; ++it) {
    int idx = tid + it * 256;
    int rr = idx >> 3, dd = (idx & 7) * 8;
    *(s16x8*)&KS[rr][dd] =
        *(const s16x8*)(Kp + (((size_t)(n * 512 + rr)) * 8 + h) * 64 + dd);
  }
#pragma unroll
  for (int ks = 0; ks < 4; ++ks)
#pragma unroll
    for (int fj = 0; fj < 4; ++fj)
      vreg[ks * 4 + fj] = *(const s16x8*)(Vb + fj * 8192 + ks * 32);
  __syncthreads();

  for (int c = 0; c < 4; ++c) {
    if (c) {
      __syncthreads();   // all waves done with KS(c-1) and vreg(c-1)
#pragma unroll
      for (int it = 0; it < 4; ++it) {
        int idx = tid + it * 256;
        int rr = idx >> 3, dd = (idx & 7) * 8;
        *(s16x8*)&KS[rr][dd] =
            *(const s16x8*)(Kp + (((size_t)(n * 512 + c * 128 + rr)) * 8 + h) * 64 + dd);
      }
#pragma unroll
      for (int ks = 0; ks < 4; ++ks)
#pragma unroll
        for (int fj = 0; fj < 4; ++fj)
          vreg[ks * 4 + fj] = *(const s16x8*)(Vb + fj * 8192 + c * 128 + ks * 32);
      __syncthreads();
    }
#pragma unroll
    for (int rt = 0; rt < 4; ++rt) {
      const int qr = w * 64 + rt * 16 + lr;
      s16x8 qf0 = *(const s16x8*)&QL[qr][lg * 8];
      s16x8 qf1 = *(const s16x8*)&QL[qr][32 + lg * 8];
      f32x4 sacc[8];
      __builtin_amdgcn_s_setprio(1);
#pragma unroll
      for (int f = 0; f < 8; ++f) {
        s16x8 b0 = *(const s16x8*)&KS[f * 16 + lr][lg * 8];
        s16x8 b1 = *(const s16x8*)&KS[f * 16 + lr][32 + lg * 8];
        f32x4 a = {};
        a = __builtin_amdgcn_mfma_f32_16x16x32_bf16(qf0, b0, a, 0, 0, 0);
        a = __builtin_amdgcn_mfma_f32_16x16x32_bf16(qf1, b1, a, 0, 0, 0);
        sacc[f] = a;
      }
      __builtin_amdgcn_s_setprio(0);

      float fs[4];
#pragma unroll
      for (int r = 0; r < 4; ++r) {
        float cm = sacc[0][r];
#pragma unroll
        for (int f = 1; f < 8; ++f) cm = fmaxf(cm, sacc[f][r]);
#pragma unroll
        for (int mk = 1; mk < 16; mk <<= 1) cm = fmaxf(cm, __shfl_xor(cm, mk));
        float mn = fmaxf(m[rt][r], cm);
        fs[r] = __expf(m[rt][r] - mn);
        m[rt][r] = mn;
        unsigned pa = lds_addr(&P[w][lg * 4 + r][lr]);
        float cs = 0.f;
#pragma unroll
        for (int f = 0; f < 8; ++f) {
          float p = __expf(sacc[f][r] - mn);
          asm volatile("ds_write_b16_d16_hi %0, %1 offset:%2"
                       :: "v"(pa), "v"(p), "i"(f * 32) : "memory");
          cs += p;
        }
#pragma unroll
        for (int mk = 1; mk < 16; mk <<= 1) cs += __shfl_xor(cs, mk);
        lsum[rt][r] = lsum[rt][r] * fs[r] + cs;
      }
#pragma unroll
      for (int fj = 0; fj < 4; ++fj)
#pragma unroll
        for (int r = 0; r < 4; ++r) oacc[rt][fj][r] *= fs[r];

      asm volatile("s_waitcnt lgkmcnt(0)" ::: "memory");
      __builtin_amdgcn_sched_barrier(0);
      __builtin_amdgcn_s_setprio(1);
#pragma unroll
      for (int ks = 0; ks < 4; ++ks) {
        s16x8 pa = *(const s16x8*)&P[w][lr][ks * 32 + lg * 8];
#pragma unroll
        for (int fj = 0; fj < 4; ++fj)
          oacc[rt][fj] = __builtin_amdgcn_mfma_f32_16x16x32_bf16(pa, vreg[ks * 4 + fj], oacc[rt][fj], 0, 0, 0);
      }
      __builtin_amdgcn_s_setprio(0);
    }
  }

#pragma unroll
  for (int rt = 0; rt < 4; ++rt)
#pragma unroll
    for (int fj = 0; fj < 4; ++fj)
#pragma unroll
      for (int r = 0; r < 4; ++r) {
        int qrow = q0 + w * 64 + rt * 16 + lg * 4 + r;
        Out[((size_t)(n * 512 + qrow)) * 512 + h * 64 + fj * 16 + lr] =
            f2bf(oacc[rt][fj][r] / lsum[rt][r]);
      }
}

// ---------------- layernorm: 1 wave per 512-elem row, fused residual ------
template<bool XBF, bool RBF, bool QIN, bool OUTBF>
__global__ __launch_bounds__(256) void ln_kernel(const void* __restrict__ Xv,
    const void* __restrict__ Rv, const float* __restrict__ onehot,
    const float* __restrict__ g, const float* __restrict__ bb,
    void* __restrict__ outv) {
  int row = blockIdx.x * 4 + (threadIdx.x >> 6);
  int l = threadIdx.x & 63;
  size_t base = (size_t)row * 512 + l * 8;
  float v[8];
  if (XBF) {
    s16x8 xv = *(const s16x8*)((const unsigned short*)Xv + base);
#pragma unroll
    for (int j = 0; j < 8; ++j) v[j] = bf2f((unsigned short)xv[j]);
  } else {
    const float* X = (const float*)Xv;
    float4 x0 = *(const float4*)(X + base);
    float4 x1 = *(const float4*)(X + base + 4);
    v[0] = x0.x; v[1] = x0.y; v[2] = x0.z; v[3] = x0.w;
    v[4] = x1.x; v[5] = x1.y; v[6] = x1.z; v[7] = x1.w;
  }
  if (RBF) {
    s16x8 rv = *(const s16x8*)((const unsigned short*)Rv + base);
#pragma unroll
    for (int j = 0; j < 8; ++j) v[j] += bf2f((unsigned short)rv[j]);
  } else {
    const float* R = (const float*)Rv;
    float4 r0 = *(const float4*)(R + base);
    float4 r1 = *(const float4*)(R + base + 4);
    v[0] += r0.x; v[1] += r0.y; v[2] += r0.z; v[3] += r0.w;
    v[4] += r1.x; v[5] += r1.y; v[6] += r1.z; v[7] += r1.w;
  }
  if (QIN) {
    size_t ob = (size_t)(row & 511) * 512 + l * 8;
    float4 o0 = *(const float4*)(onehot + ob);
    float4 o1 = *(const float4*)(onehot + ob + 4);
    v[0] += o0.x; v[1] += o0.y; v[2] += o0.z; v[3] += o0.w;
    v[4] += o1.x; v[5] += o1.y; v[6] += o1.z; v[7] += o1.w;
  }
  float s = 0.f, ss = 0.f;
#pragma unroll
  for (int j = 0; j < 8; ++j) { s += v[j]; ss += v[j] * v[j]; }
#pragma unroll
  for (int mk = 1; mk < 64; mk <<= 1) { s += __shfl_xor(s, mk); ss += __shfl_xor(ss, mk); }
  float mu = s * (1.f / 512.f);
  float inv = rsqrtf(ss * (1.f / 512.f) - mu * mu + 1e-5f);
#pragma unroll
  for (int j = 0; j < 8; ++j) {
    int e = l * 8 + j;
    float y = (v[j] - mu) * inv * g[e] + bb[e];
    if (OUTBF) ((unsigned short*)outv)[base + j] = f2bf(y);
    else ((float*)outv)[base + j] = y;
  }
}

extern "C" void kernel_launch(void* const* d_in, const int* in_sizes, int n_in,
                              void* d_out, int out_size, void* d_ws, size_t ws_size,
                              hipStream_t stream) {
  const float* value  = (const float*)d_in[0];
  const float* key_in = (const float*)d_in[1];
  const float* query  = (const float*)d_in[2];
  const int*   pi     = (const int*)d_in[3];
  const float* I_mat  = (const float*)d_in[4];
  const float* ohW    = (const float*)d_in[5];
  const float* ohb    = (const float*)d_in[6];
  const float* Wv     = (const float*)d_in[7];
  const float* Wk     = (const float*)d_in[8];
  const float* Wq     = (const float*)d_in[9];
  const float* Wo     = (const float*)d_in[10];
  const float* bo     = (const float*)d_in[11];
  const float* g1     = (const float*)d_in[12];
  const float* b1     = (const float*)d_in[13];
  const float* g2     = (const float*)d_in[14];
  const float* b2     = (const float*)d_in[15];
  const float* W1     = (const float*)d_in[16];
  const float* bf1    = (const float*)d_in[17];
  const float* W2     = (const float*)d_in[18];
  const float* bf2    = (const float*)d_in[19];

  char* ws = (char*)d_ws;
  const size_t MB = 1024 * 1024;
  unsigned short* q_p  = (unsigned short*)d_out;      // d_out as scratch
  unsigned short* k_p  = q_p + 16777216;
  unsigned short* vT     = (unsigned short*)(ws + 0);        // 32MB, [n][h][d][t]
  unsigned short* attn_o = (unsigned short*)(ws + 32 * MB);  // 32MB
  unsigned short* x_b    = (unsigned short*)(ws + 64 * MB);  // 32MB
  unsigned short* ff1h   = (unsigned short*)(ws + 0);        // 64MB half (aliases vT/attn_o)
  float*          onehot = (float*)(ws + 96 * MB);           // 1MB
  unsigned short* Wv_b   = (unsigned short*)(ws + 97 * MB);
  unsigned short* Wk_b   = Wv_b + 4096;
  unsigned short* Wq_b   = Wk_b + 4096;
  unsigned short* Wop    = Wq_b + 4096;      // 512KB packed
  unsigned short* W1p    = Wop + 262144;     // 2MB packed
  unsigned short* W2p    = W1p + 1048576;    // 2MB packed

  cast_kernel<<<4, 256, 0, stream>>>(Wv, Wv_b, 4096, 1.f);
  cast_kernel<<<4, 256, 0, stream>>>(Wk, Wk_b, 4096, 1.f);
  cast_kernel<<<4, 256, 0, stream>>>(Wq, Wq_b, 4096, 0.044194173824159216f);
  pack_b<<<128, 256, 0, stream>>>(Wo, Wop, 512, 32768);
  pack_b<<<512, 256, 0, stream>>>(W1, W1p, 2048, 131072);
  pack_b<<<512, 256, 0, stream>>>(W2, W2p, 512, 131072);
  onehot_kernel<<<512, 256, 0, stream>>>(pi, I_mat, ohW, ohb, onehot);

  dim3 gp(4096, 1);
  proj_gemm<false, 1><<<gp, 256, 0, stream>>>(value,  Wv_b, nullptr, vT,  262144, 64, 64);
  proj_gemm<false, 0><<<gp, 256, 0, stream>>>(key_in, Wk_b, nullptr, k_p, 262144, 64, 64);
  proj_gemm<true,  0><<<gp, 256, 0, stream>>>(query,  Wq_b, onehot,  q_p, 262144, 64, 64);

  attn_kernel<<<1024, 256, 0, stream>>>(q_p, k_p, vT, attn_o);

  // Wo: x_b(bf16) = attn_o @ Wo + bo
  dim3 gwo(256, 4);
  gemmF<false, true><<<gwo, 256, 0, stream>>>(
      attn_o, 512, Wop, 32, 0, 0, bo, x_b, 512, 32768, 512);
  // LN1 in place on x_b, residual = query + onehot
  ln_kernel<true, false, true, true><<<8192, 256, 0, stream>>>(x_b, query, onehot, g1, b1, x_b);

  // FFN split over 2 row-halves (M=16384 each)
  for (int hf = 0; hf < 2; ++hf) {
    const unsigned short* xh = x_b + (size_t)hf * 16384 * 512;
    dim3 gf1(128, 16);
    gemmF<true, true><<<gf1, 256, 0, stream>>>(
        xh, 512, W1p, 128, 0, 0, bf1, ff1h, 2048, 16384, 512);
    dim3 gf2(128, 4);
    gemmF<false, false><<<gf2, 256, 0, stream>>>(
        ff1h, 2048, W2p, 32, 0, 0, bf2, (float*)d_out + (size_t)hf * 16384 * 512, 512, 16384, 2048);
  }
  // LN2: X = d_out f32, R = x_b bf16 -> d_out in place
  ln_kernel<false, true, false, false><<<8192, 256, 0, stream>>>(d_out, x_b, nullptr, g2, b2, d_out);
}